// Round 9
// baseline (2420.160 us; speedup 1.0000x reference)
//
#include <hip/hip_runtime.h>
#include <stdint.h>
#include <math.h>

// DialogueSNN: B=8, S=256, V=32000, E=64, H=128, T=20 inner steps.
// All internal math in f64 to track the high-precision numpy reference
// (spike outputs are binary: one flipped threshold decision = absmax 1.0).
//
// R4: 1-deep global prefetch -> 723 cy/step (600 cy exposed mask latency).
// R6: 8-deep register pipeline -> compiler sank the loads (VGPR stayed 132),
//     got slower (872 cy/step). Plain loads CANNOT hold a pipeline.
// R7: masks staged chunk-wise into LDS via __builtin_amdgcn_global_load_lds
//     (fire-and-forget DMA, unsinkable). 128-step chunks, double-buffered
//     (2x8KB LDS); chunk c+1's DMA issued at top of chunk c, one
//     __syncthreads per chunk (vmcnt(0) drain is free: loads ~19k cy old).
//     Per-step mask reads = broadcast ds_read_b128 + 1-deep reg prefetch.
//
// Workspace: cur1 (256*8*128 f64 = 2 MB) + masks (5120*16 u64 = 640 KB).

#define BB 8
#define SS 256
#define EE 64
#define HH 128
#define VV 32000
#define TT 20
#define NG (SS*TT)   // 5120 total steps

#define TBV 128      // v-columns per block in k2 (w2s slice = 64 KB)
#define BSP 4        // batch chains per thread in k2
#define CHS 128      // steps per mask chunk (NG % CHS == 0 -> 40 chunks)
#define NCH (NG/CHS)

typedef unsigned long long u64;
typedef const __attribute__((address_space(1))) void gvoid;
typedef __attribute__((address_space(3))) void lvoid;

__global__ __launch_bounds__(HH) void k0_cur1(
    const int* __restrict__ x, const float* __restrict__ embed,
    const float* __restrict__ W1, const float* __restrict__ b1,
    double* __restrict__ cur1)
{
    int blk = blockIdx.x;          // t*BB + b
    int t = blk >> 3, b = blk & 7;
    int h = threadIdx.x;           // 0..127
    int ix = x[b*SS + t];
    const float* erow = embed + (size_t)ix * EE;
    double acc = 0.0;
    #pragma unroll
    for (int e = 0; e < EE; ++e)
        acc += (double)erow[e] * (double)W1[e*HH + h];
    acc += (double)b1[h];
    cur1[((size_t)t*BB + b)*HH + h] = acc;
}

__global__ __launch_bounds__(64) void k1_l1(
    const double* __restrict__ cur1, u64* __restrict__ masks,
    float* __restrict__ out_mem1)
{
    // one wave per block; blockIdx.x = b*2 + half; lane = h within half
    int b = blockIdx.x >> 1, half = blockIdx.x & 1;
    int lane = threadIdx.x;
    int h = half*64 + lane;
    double m = 0.0;
    double r = 0.0;   // reset at step s == spk at step s-1; heaviside(0-1)=0 init
    for (int t = 0; t < SS; ++t) {
        double cur = cur1[((size_t)t*BB + b)*HH + h];
        #pragma unroll
        for (int s = 0; s < TT; ++s) {
            m = __builtin_fma(0.95, m, cur) - r;   // chain: fma -> sub
            bool spk = m > 1.0;
            r = spk ? 1.0 : 0.0;
            u64 msk = __ballot(spk);
            if (lane == 0) masks[(size_t)(t*TT + s)*(2*BB) + b*2 + half] = msk;
        }
    }
    out_mem1[b*HH + h] = (float)m;
}

__global__ __launch_bounds__(TBV) void k2_l2(
    const float* __restrict__ W2, const float* __restrict__ b2,
    const u64* __restrict__ masks, float* __restrict__ out)
{
    __shared__ float w2s[HH][TBV];            // 64 KB, resident whole kernel
    __shared__ ulonglong2 mbuf[2][CHS*4];     // 2 x 8 KB mask chunk buffers
    const int tid = threadIdx.x;
    const int v0 = blockIdx.x * TBV;
    const int by = blockIdx.y;
    const int b0 = by * BSP;
    for (int i = tid; i < HH*TBV; i += TBV) {
        int hh = i >> 7;                      // i / TBV (TBV==128)
        w2s[hh][tid] = W2[(size_t)hh*VV + v0 + tid];
    }

    // --- mask chunk staging via global_load_lds (unsinkable DMA) ---
    // global layout: step*128B, our block's 4 chains at +by*64, 16B each.
    // call-site i covers steps i*32 + tid/4 (128 thr * 16B = 2 KB = 32 steps).
    // LDS dest = wave-uniform base + lane*16 -> linear [step][chain] layout.
    const char* mbase = (const char*)masks + (size_t)by*64 + (size_t)(tid >> 2)*128
                        + (size_t)(tid & 3)*16;
    const int wv = tid >> 6;                  // wave id (uniform per wave)
    #define STAGE(c, bsel)                                                       \
        { const char* gp0 = mbase + (size_t)(c)*(CHS*128);                       \
          char* lp0 = (char*)&mbuf[(bsel)][0] + wv*1024;                         \
          _Pragma("unroll")                                                      \
          for (int i_ = 0; i_ < CHS/32; ++i_)                                    \
              __builtin_amdgcn_global_load_lds(                                  \
                  (gvoid*)(gp0 + (size_t)i_*32*128),                             \
                  (lvoid*)(lp0 + i_*2048), 16, 0, 0); }

    STAGE(0, 0);
    __syncthreads();                          // w2s + chunk 0 ready

    const int v = v0 + tid;
    const double b2v = (double)b2[v];
    double mm[BSP], rr[BSP];
    float* outp[BSP];
    #pragma unroll
    for (int j = 0; j < BSP; ++j) {
        mm[j] = 0.0; rr[j] = 0.0;
        outp[j] = out + (size_t)(b0 + j)*SS*VV + v;
    }

    int ic = 0;                               // inner-step counter (emit at TT)
    int buf = 0;
    for (int c = 0; c < NCH; ++c) {
        if (c + 1 < NCH) STAGE(c + 1, buf ^ 1);
        const ulonglong2* mc = &mbuf[buf][0];

        ulonglong2 cm[BSP];                   // 1-deep reg prefetch (R4-proven)
        #pragma unroll
        for (int q = 0; q < BSP; ++q) cm[q] = mc[q];

        for (int sic = 0; sic < CHS; ++sic) {
            const int nsic = (sic + 1 < CHS) ? sic + 1 : sic;
            ulonglong2 nm[BSP];
            #pragma unroll
            for (int q = 0; q < BSP; ++q) nm[q] = mc[nsic*4 + q];

            const bool emit = (++ic == TT);
            if (emit) ic = 0;

            #pragma unroll
            for (int j = 0; j < BSP; ++j) {
                u64 m0 = cm[j].x, m1 = cm[j].y;
                double sum = 0.0;
                while (m0) { int hh = __builtin_ctzll(m0); m0 &= (m0 - 1);
                             sum += (double)w2s[hh][tid]; }
                while (m1) { int hh = __builtin_ctzll(m1); m1 &= (m1 - 1);
                             sum += (double)w2s[64 + hh][tid]; }
                double cur = sum + b2v;                    // matches np op order
                mm[j] = __builtin_fma(0.95, mm[j], cur) - rr[j];
                bool spk = mm[j] > 1.0;
                rr[j] = spk ? 1.0 : 0.0;
                if (emit) { *outp[j] = spk ? 1.0f : 0.0f; outp[j] += VV; }
            }
            #pragma unroll
            for (int q = 0; q < BSP; ++q) cm[q] = nm[q];
        }
        __syncthreads();                      // chunk c done; c+1's DMA landed
        buf ^= 1;
    }

    float* mem2out = out + (size_t)BB*SS*VV + (size_t)BB*HH;
    #pragma unroll
    for (int j = 0; j < BSP; ++j)
        mem2out[(size_t)(b0 + j)*VV + v] = (float)mm[j];
}

extern "C" void kernel_launch(void* const* d_in, const int* in_sizes, int n_in,
                              void* d_out, int out_size, void* d_ws, size_t ws_size,
                              hipStream_t stream)
{
    const int*   x     = (const int*)  d_in[0];
    const float* embed = (const float*)d_in[1];
    const float* W1    = (const float*)d_in[2];
    const float* b1    = (const float*)d_in[3];
    const float* W2    = (const float*)d_in[4];
    const float* b2    = (const float*)d_in[5];
    float* out = (float*)d_out;

    // workspace carve: cur1 f64 [256*8*128] then masks u64 [5120*16]
    double* cur1 = (double*)d_ws;
    u64* masks = (u64*)((char*)d_ws + (size_t)SS*BB*HH*sizeof(double));

    k0_cur1<<<SS*BB, HH, 0, stream>>>(x, embed, W1, b1, cur1);
    k1_l1<<<BB*2, 64, 0, stream>>>(cur1, masks, out + (size_t)BB*SS*VV);
    k2_l2<<<dim3(VV/TBV, BB/BSP), TBV, 0, stream>>>(W2, b2, masks, out);
}

// Round 11
// 1223.222 us; speedup vs baseline: 1.9785x; 1.9785x over previous
//
#include <hip/hip_runtime.h>
#include <stdint.h>
#include <math.h>

// DialogueSNN: B=8, S=256, V=32000, E=64, H=128, T=20 inner steps.
// All internal math in f64 to track the high-precision numpy reference
// (spike outputs are binary: one flipped threshold decision = absmax 1.0).
//
// R4/R6/R9 post-mortem: 723/872/923 cy/step across three different mask-load
// schemes -> mask latency was NEVER the bottleneck. Common factor: 1 wave/SIMD
// (occupancy 12%) + branchy serial body (8 while-loops/step) => every branch
// bubble and dependent-LDS latency fully exposed (~730 cy/step stall).
// R10: TLP attack. k2 = 512-thread blocks, BSP=1 (thread = (v, b)), grid
// (250,2): 16 waves/CU = 4 waves/SIMD; per-wave body shrinks to 1 broadcast
// mask read + <=2 sparse bit-loops + 1 f64 fma. LDS 80KB -> 2 blocks/CU.
// Mask staging stays LDS-DMA (global_load_lds), 1 call per 128-step chunk.
//
// Workspace: cur1 (256*8*128 f64 = 2 MB) + masks (5120*16 u64 = 640 KB).

#define BB 8
#define SS 256
#define EE 64
#define HH 128
#define VV 32000
#define TT 20
#define NG (SS*TT)   // 5120 total steps

#define TBV 128      // v-columns per block in k2 (w2s slice = 64 KB)
#define NTH 512      // k2 threads: 128 v-cols x 4 batches
#define CHS 128      // steps per mask chunk (NG % CHS == 0 -> 40 chunks)
#define NCH (NG/CHS)

typedef unsigned long long u64;
typedef const __attribute__((address_space(1))) void gvoid;
typedef __attribute__((address_space(3))) void lvoid;

__global__ __launch_bounds__(HH) void k0_cur1(
    const int* __restrict__ x, const float* __restrict__ embed,
    const float* __restrict__ W1, const float* __restrict__ b1,
    double* __restrict__ cur1)
{
    int blk = blockIdx.x;          // t*BB + b
    int t = blk >> 3, b = blk & 7;
    int h = threadIdx.x;           // 0..127
    int ix = x[b*SS + t];
    const float* erow = embed + (size_t)ix * EE;
    double acc = 0.0;
    #pragma unroll
    for (int e = 0; e < EE; ++e)
        acc += (double)erow[e] * (double)W1[e*HH + h];
    acc += (double)b1[h];
    cur1[((size_t)t*BB + b)*HH + h] = acc;
}

__global__ __launch_bounds__(64) void k1_l1(
    const double* __restrict__ cur1, u64* __restrict__ masks,
    float* __restrict__ out_mem1)
{
    // one wave per block; blockIdx.x = b*2 + half; lane = h within half
    int b = blockIdx.x >> 1, half = blockIdx.x & 1;
    int lane = threadIdx.x;
    int h = half*64 + lane;
    double m = 0.0;
    double r = 0.0;   // reset at step s == spk at step s-1; heaviside(0-1)=0 init
    for (int t = 0; t < SS; ++t) {
        double cur = cur1[((size_t)t*BB + b)*HH + h];
        #pragma unroll
        for (int s = 0; s < TT; ++s) {
            m = __builtin_fma(0.95, m, cur) - r;   // chain: fma -> sub
            bool spk = m > 1.0;
            r = spk ? 1.0 : 0.0;
            u64 msk = __ballot(spk);
            if (lane == 0) masks[(size_t)(t*TT + s)*(2*BB) + b*2 + half] = msk;
        }
    }
    out_mem1[b*HH + h] = (float)m;
}

__global__ __launch_bounds__(NTH, 4) void k2_l2(
    const float* __restrict__ W2, const float* __restrict__ b2,
    const u64* __restrict__ masks, float* __restrict__ out)
{
    __shared__ float w2s[HH][TBV];            // 64 KB, resident whole kernel
    __shared__ ulonglong2 mbuf[2][CHS*4];     // 2 x 8 KB mask chunk buffers
    const int tid = threadIdx.x;
    const int vl  = tid & 127;                // v within tile
    const int bq  = tid >> 7;                 // 0..3 batch within group
    const int v0 = blockIdx.x * TBV;
    const int by = blockIdx.y;                // batch group (4 batches each)
    const int b  = by*4 + bq;
    for (int i = tid; i < HH*TBV; i += NTH) {
        int hh = i >> 7;
        w2s[hh][i & 127] = W2[(size_t)hh*VV + v0 + (i & 127)];
    }

    // --- mask chunk staging via global_load_lds (unsinkable DMA) ---
    // global: step*128B; this block's 4 chains at +by*64, 16B each.
    // one call: 512 lanes x 16B = 8 KB = 128 steps. LDS dest = wave-uniform
    // base + lane*16 -> byte tid*16 = step(tid>>2)*64 + chain(tid&3)*16.
    const char* mbase = (const char*)masks + (size_t)by*64
                        + (size_t)(tid >> 2)*128 + (size_t)(tid & 3)*16;
    const int wv = tid >> 6;                  // wave id (uniform per wave)
    #define STAGE(c, bsel)                                                       \
        __builtin_amdgcn_global_load_lds(                                        \
            (gvoid*)(mbase + (size_t)(c)*(CHS*128)),                             \
            (lvoid*)((char*)&mbuf[(bsel)][0] + wv*1024), 16, 0, 0);

    STAGE(0, 0);
    __syncthreads();                          // w2s + chunk 0 ready

    const int v = v0 + vl;
    const double b2v = (double)b2[v];
    double mm = 0.0, rr = 0.0;
    float* outp = out + (size_t)b*SS*VV + v;

    int ic = 0;                               // inner-step counter (emit at TT)
    int buf = 0;
    for (int c = 0; c < NCH; ++c) {
        if (c + 1 < NCH) STAGE(c + 1, buf ^ 1);
        const ulonglong2* mc = &mbuf[buf][0];

        ulonglong2 cm = mc[bq];               // 1-deep reg prefetch
        for (int sic = 0; sic < CHS; ++sic) {
            const int nsic = (sic + 1 < CHS) ? sic + 1 : sic;
            ulonglong2 nm = mc[nsic*4 + bq];  // broadcast ds_read_b128

            const bool emit = (++ic == TT);
            if (emit) ic = 0;

            u64 m0 = cm.x, m1 = cm.y;
            double sum = 0.0;
            while (m0) { int hh = __builtin_ctzll(m0); m0 &= (m0 - 1);
                         sum += (double)w2s[hh][vl]; }
            while (m1) { int hh = __builtin_ctzll(m1); m1 &= (m1 - 1);
                         sum += (double)w2s[64 + hh][vl]; }
            double cur = sum + b2v;                    // matches np op order
            mm = __builtin_fma(0.95, mm, cur) - rr;
            bool spk = mm > 1.0;
            rr = spk ? 1.0 : 0.0;
            if (emit) { *outp = spk ? 1.0f : 0.0f; outp += VV; }
            cm = nm;
        }
        __syncthreads();                      // chunk c done; c+1's DMA landed
        buf ^= 1;
    }

    float* mem2out = out + (size_t)BB*SS*VV + (size_t)BB*HH;
    mem2out[(size_t)b*VV + v] = (float)mm;
}

extern "C" void kernel_launch(void* const* d_in, const int* in_sizes, int n_in,
                              void* d_out, int out_size, void* d_ws, size_t ws_size,
                              hipStream_t stream)
{
    const int*   x     = (const int*)  d_in[0];
    const float* embed = (const float*)d_in[1];
    const float* W1    = (const float*)d_in[2];
    const float* b1    = (const float*)d_in[3];
    const float* W2    = (const float*)d_in[4];
    const float* b2    = (const float*)d_in[5];
    float* out = (float*)d_out;

    // workspace carve: cur1 f64 [256*8*128] then masks u64 [5120*16]
    double* cur1 = (double*)d_ws;
    u64* masks = (u64*)((char*)d_ws + (size_t)SS*BB*HH*sizeof(double));

    k0_cur1<<<SS*BB, HH, 0, stream>>>(x, embed, W1, b1, cur1);
    k1_l1<<<BB*2, 64, 0, stream>>>(cur1, masks, out + (size_t)BB*SS*VV);
    k2_l2<<<dim3(VV/TBV, BB/4), NTH, 0, stream>>>(W2, b2, masks, out);
}